// Round 5
// baseline (106.960 us; speedup 1.0000x reference)
//
#include <hip/hip_runtime.h>

#define NB   16
#define CINC 32
#define HH   128
#define WWD  128
#define FF   32
#define OPSN 5
#define EPSV 1e-5f

// ws layout:
//   floats [0:64)          bnp (scale/shift)
//   int    at byte 256     counter (last-block finalize; reset by transform)
//   floats [80:65616)      partial (1024 blocks * 64)
//   bytes  at 262528       wfrag (18 frags * 64 lanes * 8 bf16 = 18432 B)
//   bytes  at 280960       xt  [16][130][130][32] bf16
#define WS_CNT_BOFF     256
#define WS_PARTIAL_FOFF 80
#define WS_WFRAG_BOFF   262528
#define WS_XT_BOFF      280960
#define WS_NEED         (280960 + (size_t)16*130*130*32*2)

typedef __attribute__((ext_vector_type(8))) short bf16x8;
typedef __attribute__((ext_vector_type(4))) float f32x4;

__device__ __forceinline__ unsigned short f2bf(float f) {
    unsigned u = __builtin_bit_cast(unsigned, f);
    u += 0x7FFFu + ((u >> 16) & 1u);
    return (unsigned short)(u >> 16);
}
__device__ __forceinline__ unsigned pack2(float lo, float hi) {
    return (unsigned)f2bf(lo) | ((unsigned)f2bf(hi) << 16);
}

// ---------------------------------------------------------------------------
// transform: x NCHW fp32 -> xt [n][hp][wp][c] bf16 (halo 0). Block swizzle:
// bid%8 == n>>1 so XCD k produces xt for n in {2k,2k+1}; the conv kernels use
// the same mapping -> xt slice (2.16 MB) stays in that XCD's L2.
// bid==2080 builds wfrag and resets the finalize counter.
// ---------------------------------------------------------------------------
__global__ __launch_bounds__(256) void transform_kernel(
    const float* __restrict__ x, const float* __restrict__ Wall,
    const int* __restrict__ opidx, unsigned short* __restrict__ xt,
    unsigned short* __restrict__ wfrag, int* __restrict__ counter)
{
    __shared__ float lds[128 * 35];
    const int bid = blockIdx.x;
    const int tid = threadIdx.x;

    if (bid == NB * 130) {
        if (tid == 0) *counter = 0;
        // wfrag[((s*2+m)*64+lane)*8+j] = W[f=m*16+(lane&15)][c=(lane>>4)*8+j][kh][kw]
        for (int idx = tid; idx < 9216; idx += 256) {
            int frag = idx >> 9;          // 0..17
            int lane = (idx >> 3) & 63;
            int j    = idx & 7;
            int s = frag >> 1, m = frag & 1;
            int kh = s / 3, kw = s - 3 * kh;
            int f = m * 16 + (lane & 15);
            int c = ((lane >> 4) << 3) + j;
            float v = Wall[((size_t)(f * OPSN + opidx[f]) * 288) + c * 9 + kh * 3 + kw];
            wfrag[idx] = f2bf(v);
        }
        return;
    }

    const int idx = bid >> 3;                      // 0..259
    const int n   = (bid & 7) * 2 + (idx / 130);   // XCD-aligned n
    const int hp  = idx % 130;

    unsigned short* rowp = xt + (size_t)(n * 130 + hp) * 130 * 32;
    uint4 zz = make_uint4(0, 0, 0, 0);

    if (hp == 0 || hp == 129) {
        for (int c = tid; c < 520; c += 256) ((uint4*)rowp)[c] = zz;
        return;
    }

    const int h = hp - 1;
    const float* xr = x + ((size_t)n * CINC * HH + h) * WWD;
    const int c  = tid >> 3;
    const int wq = tid & 7;
#pragma unroll
    for (int it = 0; it < 4; ++it) {
        int w4 = wq + it * 8;
        float4 v = ((const float4*)(xr + (size_t)c * (HH * WWD)))[w4];
        int w = w4 * 4;
        lds[(w + 0) * 35 + c] = v.x;
        lds[(w + 1) * 35 + c] = v.y;
        lds[(w + 2) * 35 + c] = v.z;
        lds[(w + 3) * 35 + c] = v.w;
    }
    __syncthreads();
    for (int cc = tid; cc < 512; cc += 256) {
        int p = cc >> 2, k = cc & 3;
        const float* s = &lds[p * 35 + k * 8];
        uint4 o;
        o.x = pack2(s[0], s[1]); o.y = pack2(s[2], s[3]);
        o.z = pack2(s[4], s[5]); o.w = pack2(s[6], s[7]);
        ((uint4*)rowp)[4 + cc] = o;
    }
    if (tid < 4)       ((uint4*)rowp)[tid] = zz;
    else if (tid < 8)  ((uint4*)rowp)[129 * 4 + tid - 4] = zz;
}

// ---------------------------------------------------------------------------
// conv_stats: conv into registers -> per-block per-filter (sum, sumsq)
// partials; the LAST block (atomic counter) reduces all 1024 partials and
// writes bnp (scale/shift). Threadfence-reduction pattern: deterministic
// (finalizer reads a fixed array in fixed order), no co-residency assumption.
// ---------------------------------------------------------------------------
__global__ __launch_bounds__(256) void conv_stats_kernel(
    const unsigned short* __restrict__ xt,
    const unsigned short* __restrict__ wfrag,
    float* __restrict__ partial, int* __restrict__ counter,
    const float* __restrict__ gamma, const float* __restrict__ beta,
    float* __restrict__ bnp)
{
    __shared__ float red[4][64];
    __shared__ float rs[256];
    __shared__ float tot[64];
    __shared__ int lastflag;

    const int bid  = blockIdx.x;
    const int tid  = threadIdx.x;
    const int n    = (bid & 7) * 2 + ((bid >> 3) & 1);
    const int rest = bid >> 4;
    const int h0   = (rest & 31) * 4;
    const int wh   = rest >> 5;
    const int lane = tid & 63;
    const int wv   = tid >> 6;
    const int w0   = wh * 64 + wv * 16;
    const int l15  = lane & 15, lhi = lane >> 4;

    bf16x8 wfr[18];
#pragma unroll
    for (int i = 0; i < 18; ++i)
        wfr[i] = *(const bf16x8*)(wfrag + (i * 64 + lane) * 8);

    const unsigned short* xbase = xt + (size_t)n * 130 * 130 * 32;
    const int laneoff = l15 * 32 + lhi * 8;

    float s8[8], q8[8];
#pragma unroll
    for (int j = 0; j < 8; ++j) { s8[j] = 0.f; q8[j] = 0.f; }

    for (int h = h0; h < h0 + 4; ++h) {
        f32x4 acc0 = {0.f, 0.f, 0.f, 0.f};
        f32x4 acc1 = {0.f, 0.f, 0.f, 0.f};
#pragma unroll
        for (int kh = 0; kh < 3; ++kh) {
            const unsigned short* rp = xbase + ((size_t)(h + kh) * 130 + w0) * 32 + laneoff;
#pragma unroll
            for (int kw = 0; kw < 3; ++kw) {
                bf16x8 b = *(const bf16x8*)(rp + kw * 32);
                int s = kh * 3 + kw;
                acc0 = __builtin_amdgcn_mfma_f32_16x16x32_bf16(wfr[2*s],   b, acc0, 0, 0, 0);
                acc1 = __builtin_amdgcn_mfma_f32_16x16x32_bf16(wfr[2*s+1], b, acc1, 0, 0, 0);
            }
        }
#pragma unroll
        for (int r = 0; r < 4; ++r) {
            float v0 = acc0[r], v1 = acc1[r];
            s8[r]     += v0;  q8[r]     += v0 * v0;
            s8[4 + r] += v1;  q8[4 + r] += v1 * v1;
        }
    }

    // butterfly over the 16 pixel-lanes (xor<16 keeps lhi group intact)
#pragma unroll
    for (int m = 1; m < 16; m <<= 1) {
#pragma unroll
        for (int j = 0; j < 8; ++j) {
            s8[j] += __shfl_xor(s8[j], m, 64);
            q8[j] += __shfl_xor(q8[j], m, 64);
        }
    }
    if (l15 == 0) {
#pragma unroll
        for (int j = 0; j < 8; ++j) {
            int f = (j < 4) ? (lhi * 4 + j) : (16 + lhi * 4 + (j - 4));
            red[wv][f]      = s8[j];
            red[wv][32 + f] = q8[j];
        }
    }
    __syncthreads();
    if (tid < 64)
        partial[(size_t)bid * 64 + tid] =
            red[0][tid] + red[1][tid] + red[2][tid] + red[3][tid];

    __threadfence();            // push this block's partials to device scope
    __syncthreads();
    if (tid == 0)
        lastflag = (atomicAdd(counter, 1) == 1023) ? 1 : 0;
    __syncthreads();

    if (lastflag) {
        __threadfence();        // acquire: see all blocks' partials
        const int slot = tid & 63;
        const int q    = tid >> 6;
        float s = 0.f;
        for (int i = q * 256; i < q * 256 + 256; ++i)
            s += partial[(size_t)i * 64 + slot];     // 256 B/row, wave-coalesced
        rs[tid] = s;
        __syncthreads();
        if (tid < 64)
            tot[tid] = rs[tid] + rs[tid + 64] + rs[tid + 128] + rs[tid + 192];
        __syncthreads();
        if (tid < 32) {
            float cnt  = (float)(NB * HH * WWD);
            float mean = tot[tid] / cnt;
            float var  = tot[32 + tid] / cnt - mean * mean;
            float sc   = gamma[tid] * rsqrtf(var + EPSV);
            bnp[tid]      = sc;
            bnp[FF + tid] = beta[tid] - mean * sc;
        }
    }
}

// ---------------------------------------------------------------------------
// conv_apply: recompute conv, fused BN+ReLU, single final write.
// ---------------------------------------------------------------------------
__global__ __launch_bounds__(256) void conv_apply_kernel(
    const unsigned short* __restrict__ xt,
    const unsigned short* __restrict__ wfrag,
    const float* __restrict__ bnp, float* __restrict__ out)
{
    __shared__ float bns[64];
    const int bid  = blockIdx.x;
    const int tid  = threadIdx.x;
    if (tid < 64) bns[tid] = bnp[tid];

    const int n    = (bid & 7) * 2 + ((bid >> 3) & 1);
    const int rest = bid >> 4;
    const int h0   = (rest & 31) * 4;
    const int wh   = rest >> 5;
    const int lane = tid & 63;
    const int wv   = tid >> 6;
    const int w0   = wh * 64 + wv * 16;
    const int l15  = lane & 15, lhi = lane >> 4;

    bf16x8 wfr[18];
#pragma unroll
    for (int i = 0; i < 18; ++i)
        wfr[i] = *(const bf16x8*)(wfrag + (i * 64 + lane) * 8);

    const unsigned short* xbase = xt + (size_t)n * 130 * 130 * 32;
    const int laneoff = l15 * 32 + lhi * 8;

    __syncthreads();   // bns ready
    float sc0[4], sh0[4], sc1[4], sh1[4];
#pragma unroll
    for (int r = 0; r < 4; ++r) {
        int f0 = lhi * 4 + r, f1 = 16 + lhi * 4 + r;
        sc0[r] = bns[f0]; sh0[r] = bns[32 + f0];
        sc1[r] = bns[f1]; sh1[r] = bns[32 + f1];
    }

    for (int h = h0; h < h0 + 4; ++h) {
        f32x4 acc0 = {0.f, 0.f, 0.f, 0.f};
        f32x4 acc1 = {0.f, 0.f, 0.f, 0.f};
#pragma unroll
        for (int kh = 0; kh < 3; ++kh) {
            const unsigned short* rp = xbase + ((size_t)(h + kh) * 130 + w0) * 32 + laneoff;
#pragma unroll
            for (int kw = 0; kw < 3; ++kw) {
                bf16x8 b = *(const bf16x8*)(rp + kw * 32);
                int s = kh * 3 + kw;
                acc0 = __builtin_amdgcn_mfma_f32_16x16x32_bf16(wfr[2*s],   b, acc0, 0, 0, 0);
                acc1 = __builtin_amdgcn_mfma_f32_16x16x32_bf16(wfr[2*s+1], b, acc1, 0, 0, 0);
            }
        }
        float* ob = out + (size_t)(n * FF + lhi * 4) * (HH * WWD) + h * WWD + w0 + l15;
#pragma unroll
        for (int r = 0; r < 4; ++r) {
            ob[(size_t)r * (HH * WWD)] =
                fmaxf(fmaf(acc0[r], sc0[r], sh0[r]), 0.f);
            ob[(size_t)r * (HH * WWD) + 16 * (HH * WWD)] =
                fmaxf(fmaf(acc1[r], sc1[r], sh1[r]), 0.f);
        }
    }
}

// ======================= fallback (fp32 VALU, small-ws) =====================
__global__ __launch_bounds__(256) void conv_kernel(
    const float* __restrict__ x, const float* __restrict__ Wall,
    const int* __restrict__ opidx, float* __restrict__ out)
{
    __shared__ float wlds[FF * 289];
    __shared__ float xlds[8 * 3 * 132];
    const int tid = threadIdx.x;
    const int h = blockIdx.x;
    const int n = blockIdx.y;
    for (int i = tid; i < FF * 288; i += 256) {
        int f = i / 288;
        int r = i - f * 288;
        int op = opidx[f];
        wlds[f * 289 + r] = Wall[(f * OPSN + op) * 288 + r];
    }
    const int f = tid & 31;
    const int wg = tid >> 5;
    const int w0 = wg << 4;
    float acc[16];
#pragma unroll
    for (int i = 0; i < 16; ++i) acc[i] = 0.f;
    const float* xn = x + (size_t)n * CINC * HH * WWD;
    for (int cc = 0; cc < 4; ++cc) {
        __syncthreads();
        for (int i = tid; i < 8 * 3 * 132; i += 256) {
            int c8 = i / (3 * 132);
            int rem = i - c8 * (3 * 132);
            int r = rem / 132;
            int wp = rem - r * 132;
            int hin = h + r - 1;
            int win = wp - 1;
            float v = 0.f;
            if ((unsigned)hin < HH && (unsigned)win < WWD)
                v = xn[((cc * 8 + c8) * HH + hin) * WWD + win];
            xlds[i] = v;
        }
        __syncthreads();
#pragma unroll
        for (int c8 = 0; c8 < 8; ++c8) {
            const int c = cc * 8 + c8;
            float wv[9];
#pragma unroll
            for (int k = 0; k < 9; ++k) wv[k] = wlds[f * 289 + c * 9 + k];
#pragma unroll
            for (int kh = 0; kh < 3; ++kh) {
                float xr[20];
                const float4* p = (const float4*)&xlds[(c8 * 3 + kh) * 132 + w0];
#pragma unroll
                for (int j = 0; j < 5; ++j) {
                    float4 v = p[j];
                    xr[j * 4 + 0] = v.x; xr[j * 4 + 1] = v.y;
                    xr[j * 4 + 2] = v.z; xr[j * 4 + 3] = v.w;
                }
#pragma unroll
                for (int kw = 0; kw < 3; ++kw) {
                    float wgt = wv[kh * 3 + kw];
#pragma unroll
                    for (int i = 0; i < 16; ++i)
                        acc[i] = fmaf(xr[i + kw], wgt, acc[i]);
                }
            }
        }
    }
    float* op_ = out + (((size_t)(n * FF + f) * HH + h) * WWD + w0);
#pragma unroll
    for (int j = 0; j < 4; ++j)
        ((float4*)op_)[j] = make_float4(acc[j * 4], acc[j * 4 + 1],
                                        acc[j * 4 + 2], acc[j * 4 + 3]);
}

__global__ __launch_bounds__(256) void stats_kernel(
    const float* __restrict__ out, const float* __restrict__ gamma,
    const float* __restrict__ beta, float* __restrict__ ws)
{
    __shared__ float ssum[256], ssq[256];
    const int f = blockIdx.x;
    const int tid = threadIdx.x;
    float s = 0.f, q = 0.f;
    for (int n = 0; n < NB; ++n) {
        const float4* p = (const float4*)(out + (size_t)(n * FF + f) * HH * WWD);
        for (int i = tid; i < HH * WWD / 4; i += 256) {
            float4 v = p[i];
            s += v.x + v.y + v.z + v.w;
            q += v.x * v.x + v.y * v.y + v.z * v.z + v.w * v.w;
        }
    }
    ssum[tid] = s; ssq[tid] = q;
    __syncthreads();
    for (int st = 128; st > 0; st >>= 1) {
        if (tid < st) { ssum[tid] += ssum[tid + st]; ssq[tid] += ssq[tid + st]; }
        __syncthreads();
    }
    if (tid == 0) {
        float cnt = (float)(NB * HH * WWD);
        float mean = ssum[0] / cnt;
        float var = ssq[0] / cnt - mean * mean;
        float sc = gamma[f] * rsqrtf(var + EPSV);
        ws[f] = sc;
        ws[FF + f] = beta[f] - mean * sc;
    }
}

__global__ __launch_bounds__(256) void apply_kernel(
    float* __restrict__ out, const float* __restrict__ bnp)
{
    const int total4 = NB * FF * HH * WWD / 4;
    for (int i = blockIdx.x * 256 + threadIdx.x; i < total4; i += gridDim.x * 256) {
        int f = (i >> 12) & 31;
        float sc = bnp[f], sh = bnp[FF + f];
        float4 v = ((const float4*)out)[i];
        v.x = fmaxf(fmaf(v.x, sc, sh), 0.f);
        v.y = fmaxf(fmaf(v.y, sc, sh), 0.f);
        v.z = fmaxf(fmaf(v.z, sc, sh), 0.f);
        v.w = fmaxf(fmaf(v.w, sc, sh), 0.f);
        ((float4*)out)[i] = v;
    }
}
// ===========================================================================

extern "C" void kernel_launch(void* const* d_in, const int* in_sizes, int n_in,
                              void* d_out, int out_size, void* d_ws, size_t ws_size,
                              hipStream_t stream) {
    const float* x     = (const float*)d_in[0];
    const float* Wall  = (const float*)d_in[1];
    const float* gamma = (const float*)d_in[2];
    const float* beta  = (const float*)d_in[3];
    const int*   opidx = (const int*)d_in[4];
    float* out = (float*)d_out;
    float* ws  = (float*)d_ws;

    if (ws_size >= WS_NEED) {
        float*          bnp     = ws;
        int*            counter = (int*)((char*)d_ws + WS_CNT_BOFF);
        float*          partial = ws + WS_PARTIAL_FOFF;
        unsigned short* wfrag   = (unsigned short*)((char*)d_ws + WS_WFRAG_BOFF);
        unsigned short* xt      = (unsigned short*)((char*)d_ws + WS_XT_BOFF);

        transform_kernel<<<NB * 130 + 1, 256, 0, stream>>>(x, Wall, opidx, xt, wfrag, counter);
        conv_stats_kernel<<<1024, 256, 0, stream>>>(xt, wfrag, partial, counter,
                                                    gamma, beta, bnp);
        conv_apply_kernel<<<1024, 256, 0, stream>>>(xt, wfrag, bnp, out);
    } else {
        dim3 gridc(HH, NB);
        conv_kernel<<<gridc, 256, 0, stream>>>(x, Wall, opidx, out);
        stats_kernel<<<FF, 256, 0, stream>>>(out, gamma, beta, ws);
        apply_kernel<<<2048, 256, 0, stream>>>(out, ws);
    }
}

// Round 6
// 47.567 us; speedup vs baseline: 2.2486x; 2.2486x over previous
//
#include <hip/hip_runtime.h>

#define NB   16
#define CINC 32
#define HH   128
#define WWD  128
#define FF   32
#define OPSN 5
#define EPSV 1e-5f

// ws layout:
//   floats [0:64)          bnp (scale/shift)
//   floats [64:65600)      partial (1024 blocks * 64)
//   bytes  at 262400       wfrag (18 frags * 64 lanes * 8 bf16 = 18432 B)
//   bytes  at 280832       xt  [16][130][130][32] bf16
#define WS_PARTIAL_FOFF 64
#define WS_WFRAG_BOFF   262400
#define WS_XT_BOFF      280832
#define WS_NEED         (280832 + (size_t)16*130*130*32*2)

typedef __attribute__((ext_vector_type(8))) short bf16x8;
typedef __attribute__((ext_vector_type(4))) float f32x4;

__device__ __forceinline__ unsigned short f2bf(float f) {
    unsigned u = __builtin_bit_cast(unsigned, f);
    u += 0x7FFFu + ((u >> 16) & 1u);
    return (unsigned short)(u >> 16);
}
__device__ __forceinline__ unsigned pack2(float lo, float hi) {
    return (unsigned)f2bf(lo) | ((unsigned)f2bf(hi) << 16);
}

// ---------------------------------------------------------------------------
// transform: x NCHW fp32 -> xt [n][hp][wp][c] bf16 (halo 0). Block swizzle:
// bid%8 == n>>1 so XCD k produces xt for n in {2k,2k+1}; conv kernels use the
// same mapping -> xt slice (2.16 MB) stays in that XCD's L2.
// bid==2080 builds wfrag.
// ---------------------------------------------------------------------------
__global__ __launch_bounds__(256) void transform_kernel(
    const float* __restrict__ x, const float* __restrict__ Wall,
    const int* __restrict__ opidx, unsigned short* __restrict__ xt,
    unsigned short* __restrict__ wfrag)
{
    __shared__ float lds[128 * 35];
    const int bid = blockIdx.x;
    const int tid = threadIdx.x;

    if (bid == NB * 130) {
        // wfrag[((s*2+m)*64+lane)*8+j] = W[f=m*16+(lane&15)][c=(lane>>4)*8+j][kh][kw]
        for (int idx = tid; idx < 9216; idx += 256) {
            int frag = idx >> 9;          // 0..17
            int lane = (idx >> 3) & 63;
            int j    = idx & 7;
            int s = frag >> 1, m = frag & 1;
            int kh = s / 3, kw = s - 3 * kh;
            int f = m * 16 + (lane & 15);
            int c = ((lane >> 4) << 3) + j;
            float v = Wall[((size_t)(f * OPSN + opidx[f]) * 288) + c * 9 + kh * 3 + kw];
            wfrag[idx] = f2bf(v);
        }
        return;
    }

    const int idx = bid >> 3;                      // 0..259
    const int n   = (bid & 7) * 2 + (idx / 130);   // XCD-aligned n
    const int hp  = idx % 130;

    unsigned short* rowp = xt + (size_t)(n * 130 + hp) * 130 * 32;
    uint4 zz = make_uint4(0, 0, 0, 0);

    if (hp == 0 || hp == 129) {
        for (int c = tid; c < 520; c += 256) ((uint4*)rowp)[c] = zz;
        return;
    }

    const int h = hp - 1;
    const float* xr = x + ((size_t)n * CINC * HH + h) * WWD;
    const int c  = tid >> 3;
    const int wq = tid & 7;
#pragma unroll
    for (int it = 0; it < 4; ++it) {
        int w4 = wq + it * 8;
        float4 v = ((const float4*)(xr + (size_t)c * (HH * WWD)))[w4];
        int w = w4 * 4;
        lds[(w + 0) * 35 + c] = v.x;
        lds[(w + 1) * 35 + c] = v.y;
        lds[(w + 2) * 35 + c] = v.z;
        lds[(w + 3) * 35 + c] = v.w;
    }
    __syncthreads();
    for (int cc = tid; cc < 512; cc += 256) {
        int p = cc >> 2, k = cc & 3;
        const float* s = &lds[p * 35 + k * 8];
        uint4 o;
        o.x = pack2(s[0], s[1]); o.y = pack2(s[2], s[3]);
        o.z = pack2(s[4], s[5]); o.w = pack2(s[6], s[7]);
        ((uint4*)rowp)[4 + cc] = o;
    }
    if (tid < 4)       ((uint4*)rowp)[tid] = zz;
    else if (tid < 8)  ((uint4*)rowp)[129 * 4 + tid - 4] = zz;
}

// -------- shared conv helpers: 9-fragment load + 18-MFMA step ---------------
#define LOADB(arr, hh)                                                          \
    {                                                                           \
        _Pragma("unroll")                                                       \
        for (int kh = 0; kh < 3; ++kh) {                                        \
            const unsigned short* rp =                                          \
                xbase + ((size_t)((hh) + kh) * 130 + w0) * 32 + laneoff;        \
            arr[kh * 3 + 0] = *(const bf16x8*)(rp);                             \
            arr[kh * 3 + 1] = *(const bf16x8*)(rp + 32);                        \
            arr[kh * 3 + 2] = *(const bf16x8*)(rp + 64);                        \
        }                                                                       \
    }

#define MFMA18(arr, acc0, acc1)                                                 \
    {                                                                           \
        _Pragma("unroll")                                                       \
        for (int s = 0; s < 9; ++s) {                                           \
            acc0 = __builtin_amdgcn_mfma_f32_16x16x32_bf16(wfr[2*s],   arr[s], acc0, 0, 0, 0); \
            acc1 = __builtin_amdgcn_mfma_f32_16x16x32_bf16(wfr[2*s+1], arr[s], acc1, 0, 0, 0); \
        }                                                                       \
    }

// ---------------------------------------------------------------------------
// conv_stats: conv into registers (double-buffered B-fragments) -> per-block
// per-filter (sum, sumsq) partials. Grid 1024 x 256.
// ---------------------------------------------------------------------------
__global__ __launch_bounds__(256, 2) void conv_stats_kernel(
    const unsigned short* __restrict__ xt,
    const unsigned short* __restrict__ wfrag,
    float* __restrict__ partial)
{
    __shared__ float red[4][64];
    const int bid  = blockIdx.x;
    const int tid  = threadIdx.x;
    const int n    = (bid & 7) * 2 + ((bid >> 3) & 1);
    const int rest = bid >> 4;
    const int h0   = (rest & 31) * 4;
    const int wh   = rest >> 5;
    const int lane = tid & 63;
    const int wv   = tid >> 6;
    const int w0   = wh * 64 + wv * 16;
    const int l15  = lane & 15, lhi = lane >> 4;

    bf16x8 wfr[18];
#pragma unroll
    for (int i = 0; i < 18; ++i)
        wfr[i] = *(const bf16x8*)(wfrag + (i * 64 + lane) * 8);

    const unsigned short* xbase = xt + (size_t)n * 130 * 130 * 32;
    const int laneoff = l15 * 32 + lhi * 8;

    float s8[8], q8[8];
#pragma unroll
    for (int j = 0; j < 8; ++j) { s8[j] = 0.f; q8[j] = 0.f; }

    bf16x8 bA[9], bB[9];
    LOADB(bA, h0);
    LOADB(bB, h0 + 1);

#define STEP_STATS(arr)                                                         \
    {                                                                           \
        f32x4 acc0 = {0.f, 0.f, 0.f, 0.f};                                      \
        f32x4 acc1 = {0.f, 0.f, 0.f, 0.f};                                      \
        MFMA18(arr, acc0, acc1);                                                \
        _Pragma("unroll")                                                       \
        for (int r = 0; r < 4; ++r) {                                           \
            float v0 = acc0[r], v1 = acc1[r];                                   \
            s8[r]     += v0;  q8[r]     += v0 * v0;                             \
            s8[4 + r] += v1;  q8[4 + r] += v1 * v1;                             \
        }                                                                       \
    }

    STEP_STATS(bA);
    LOADB(bA, h0 + 2);
    STEP_STATS(bB);
    LOADB(bB, h0 + 3);
    STEP_STATS(bA);
    STEP_STATS(bB);
#undef STEP_STATS

    // butterfly over the 16 pixel-lanes (xor<16 keeps lhi group intact)
#pragma unroll
    for (int m = 1; m < 16; m <<= 1) {
#pragma unroll
        for (int j = 0; j < 8; ++j) {
            s8[j] += __shfl_xor(s8[j], m, 64);
            q8[j] += __shfl_xor(q8[j], m, 64);
        }
    }
    if (l15 == 0) {
#pragma unroll
        for (int j = 0; j < 8; ++j) {
            int f = (j < 4) ? (lhi * 4 + j) : (16 + lhi * 4 + (j - 4));
            red[wv][f]      = s8[j];
            red[wv][32 + f] = q8[j];
        }
    }
    __syncthreads();
    if (tid < 64)
        partial[(size_t)bid * 64 + tid] =
            red[0][tid] + red[1][tid] + red[2][tid] + red[3][tid];
}

// ---------------------------------------------------------------------------
// stats2: 32 blocks (one per filter) reduce 1024 partials -> scale/shift
// ---------------------------------------------------------------------------
__global__ __launch_bounds__(256) void stats2_kernel(
    const float* __restrict__ partial, const float* __restrict__ gamma,
    const float* __restrict__ beta, float* __restrict__ bnp)
{
    __shared__ float rs[256], rq[256];
    const int f = blockIdx.x;
    const int tid = threadIdx.x;
    float s = 0.f, q = 0.f;
#pragma unroll
    for (int k = 0; k < 4; ++k) {
        const float* p = partial + (size_t)(tid * 4 + k) * 64;
        s += p[f];
        q += p[32 + f];
    }
    rs[tid] = s; rq[tid] = q;
    __syncthreads();
    for (int st = 128; st > 0; st >>= 1) {
        if (tid < st) { rs[tid] += rs[tid + st]; rq[tid] += rq[tid + st]; }
        __syncthreads();
    }
    if (tid == 0) {
        float cnt = (float)(NB * HH * WWD);
        float mean = rs[0] / cnt;
        float var  = rq[0] / cnt - mean * mean;
        float sc = gamma[f] * rsqrtf(var + EPSV);
        bnp[f]      = sc;
        bnp[FF + f] = beta[f] - mean * sc;
    }
}

// ---------------------------------------------------------------------------
// conv_apply: recompute conv (double-buffered B-fragments), fused BN+ReLU,
// single final write.
// ---------------------------------------------------------------------------
__global__ __launch_bounds__(256, 2) void conv_apply_kernel(
    const unsigned short* __restrict__ xt,
    const unsigned short* __restrict__ wfrag,
    const float* __restrict__ bnp, float* __restrict__ out)
{
    __shared__ float bns[64];
    const int bid  = blockIdx.x;
    const int tid  = threadIdx.x;
    if (tid < 64) bns[tid] = bnp[tid];

    const int n    = (bid & 7) * 2 + ((bid >> 3) & 1);
    const int rest = bid >> 4;
    const int h0   = (rest & 31) * 4;
    const int wh   = rest >> 5;
    const int lane = tid & 63;
    const int wv   = tid >> 6;
    const int w0   = wh * 64 + wv * 16;
    const int l15  = lane & 15, lhi = lane >> 4;

    bf16x8 wfr[18];
#pragma unroll
    for (int i = 0; i < 18; ++i)
        wfr[i] = *(const bf16x8*)(wfrag + (i * 64 + lane) * 8);

    const unsigned short* xbase = xt + (size_t)n * 130 * 130 * 32;
    const int laneoff = l15 * 32 + lhi * 8;

    bf16x8 bA[9], bB[9];
    LOADB(bA, h0);
    LOADB(bB, h0 + 1);

    __syncthreads();   // bns ready

    float* ob = out + (size_t)(n * FF + lhi * 4) * (HH * WWD) + h0 * WWD + w0 + l15;

#define STEP_APPLY(arr, hh)                                                     \
    {                                                                           \
        f32x4 acc0 = {0.f, 0.f, 0.f, 0.f};                                      \
        f32x4 acc1 = {0.f, 0.f, 0.f, 0.f};                                      \
        MFMA18(arr, acc0, acc1);                                                \
        _Pragma("unroll")                                                       \
        for (int r = 0; r < 4; ++r) {                                           \
            int f0 = lhi * 4 + r, f1 = 16 + lhi * 4 + r;                        \
            ob[(size_t)r * (HH * WWD) + (hh) * WWD] =                           \
                fmaxf(fmaf(acc0[r], bns[f0], bns[32 + f0]), 0.f);               \
            ob[(size_t)r * (HH * WWD) + 16 * (HH * WWD) + (hh) * WWD] =         \
                fmaxf(fmaf(acc1[r], bns[f1], bns[32 + f1]), 0.f);               \
        }                                                                       \
    }

    STEP_APPLY(bA, 0);
    LOADB(bA, h0 + 2);
    STEP_APPLY(bB, 1);
    LOADB(bB, h0 + 3);
    STEP_APPLY(bA, 2);
    STEP_APPLY(bB, 3);
#undef STEP_APPLY
}

// ======================= fallback (fp32 VALU, small-ws) =====================
__global__ __launch_bounds__(256) void conv_kernel(
    const float* __restrict__ x, const float* __restrict__ Wall,
    const int* __restrict__ opidx, float* __restrict__ out)
{
    __shared__ float wlds[FF * 289];
    __shared__ float xlds[8 * 3 * 132];
    const int tid = threadIdx.x;
    const int h = blockIdx.x;
    const int n = blockIdx.y;
    for (int i = tid; i < FF * 288; i += 256) {
        int f = i / 288;
        int r = i - f * 288;
        int op = opidx[f];
        wlds[f * 289 + r] = Wall[(f * OPSN + op) * 288 + r];
    }
    const int f = tid & 31;
    const int wg = tid >> 5;
    const int w0 = wg << 4;
    float acc[16];
#pragma unroll
    for (int i = 0; i < 16; ++i) acc[i] = 0.f;
    const float* xn = x + (size_t)n * CINC * HH * WWD;
    for (int cc = 0; cc < 4; ++cc) {
        __syncthreads();
        for (int i = tid; i < 8 * 3 * 132; i += 256) {
            int c8 = i / (3 * 132);
            int rem = i - c8 * (3 * 132);
            int r = rem / 132;
            int wp = rem - r * 132;
            int hin = h + r - 1;
            int win = wp - 1;
            float v = 0.f;
            if ((unsigned)hin < HH && (unsigned)win < WWD)
                v = xn[((cc * 8 + c8) * HH + hin) * WWD + win];
            xlds[i] = v;
        }
        __syncthreads();
#pragma unroll
        for (int c8 = 0; c8 < 8; ++c8) {
            const int c = cc * 8 + c8;
            float wv[9];
#pragma unroll
            for (int k = 0; k < 9; ++k) wv[k] = wlds[f * 289 + c * 9 + k];
#pragma unroll
            for (int kh = 0; kh < 3; ++kh) {
                float xr[20];
                const float4* p = (const float4*)&xlds[(c8 * 3 + kh) * 132 + w0];
#pragma unroll
                for (int j = 0; j < 5; ++j) {
                    float4 v = p[j];
                    xr[j * 4 + 0] = v.x; xr[j * 4 + 1] = v.y;
                    xr[j * 4 + 2] = v.z; xr[j * 4 + 3] = v.w;
                }
#pragma unroll
                for (int kw = 0; kw < 3; ++kw) {
                    float wgt = wv[kh * 3 + kw];
#pragma unroll
                    for (int i = 0; i < 16; ++i)
                        acc[i] = fmaf(xr[i + kw], wgt, acc[i]);
                }
            }
        }
    }
    float* op_ = out + (((size_t)(n * FF + f) * HH + h) * WWD + w0);
#pragma unroll
    for (int j = 0; j < 4; ++j)
        ((float4*)op_)[j] = make_float4(acc[j * 4], acc[j * 4 + 1],
                                        acc[j * 4 + 2], acc[j * 4 + 3]);
}

__global__ __launch_bounds__(256) void stats_kernel(
    const float* __restrict__ out, const float* __restrict__ gamma,
    const float* __restrict__ beta, float* __restrict__ ws)
{
    __shared__ float ssum[256], ssq[256];
    const int f = blockIdx.x;
    const int tid = threadIdx.x;
    float s = 0.f, q = 0.f;
    for (int n = 0; n < NB; ++n) {
        const float4* p = (const float4*)(out + (size_t)(n * FF + f) * HH * WWD);
        for (int i = tid; i < HH * WWD / 4; i += 256) {
            float4 v = p[i];
            s += v.x + v.y + v.z + v.w;
            q += v.x * v.x + v.y * v.y + v.z * v.z + v.w * v.w;
        }
    }
    ssum[tid] = s; ssq[tid] = q;
    __syncthreads();
    for (int st = 128; st > 0; st >>= 1) {
        if (tid < st) { ssum[tid] += ssum[tid + st]; ssq[tid] += ssq[tid + st]; }
        __syncthreads();
    }
    if (tid == 0) {
        float cnt = (float)(NB * HH * WWD);
        float mean = ssum[0] / cnt;
        float var = ssq[0] / cnt - mean * mean;
        float sc = gamma[f] * rsqrtf(var + EPSV);
        ws[f] = sc;
        ws[FF + f] = beta[f] - mean * sc;
    }
}

__global__ __launch_bounds__(256) void apply_kernel(
    float* __restrict__ out, const float* __restrict__ bnp)
{
    const int total4 = NB * FF * HH * WWD / 4;
    for (int i = blockIdx.x * 256 + threadIdx.x; i < total4; i += gridDim.x * 256) {
        int f = (i >> 12) & 31;
        float sc = bnp[f], sh = bnp[FF + f];
        float4 v = ((const float4*)out)[i];
        v.x = fmaxf(fmaf(v.x, sc, sh), 0.f);
        v.y = fmaxf(fmaf(v.y, sc, sh), 0.f);
        v.z = fmaxf(fmaf(v.z, sc, sh), 0.f);
        v.w = fmaxf(fmaf(v.w, sc, sh), 0.f);
        ((float4*)out)[i] = v;
    }
}
// ===========================================================================

extern "C" void kernel_launch(void* const* d_in, const int* in_sizes, int n_in,
                              void* d_out, int out_size, void* d_ws, size_t ws_size,
                              hipStream_t stream) {
    const float* x     = (const float*)d_in[0];
    const float* Wall  = (const float*)d_in[1];
    const float* gamma = (const float*)d_in[2];
    const float* beta  = (const float*)d_in[3];
    const int*   opidx = (const int*)d_in[4];
    float* out = (float*)d_out;
    float* ws  = (float*)d_ws;

    if (ws_size >= WS_NEED) {
        float*          bnp     = ws;
        float*          partial = ws + WS_PARTIAL_FOFF;
        unsigned short* wfrag   = (unsigned short*)((char*)d_ws + WS_WFRAG_BOFF);
        unsigned short* xt      = (unsigned short*)((char*)d_ws + WS_XT_BOFF);

        transform_kernel<<<NB * 130 + 1, 256, 0, stream>>>(x, Wall, opidx, xt, wfrag);
        conv_stats_kernel<<<1024, 256, 0, stream>>>(xt, wfrag, partial);
        stats2_kernel<<<FF, 256, 0, stream>>>(partial, gamma, beta, bnp);
        conv_apply_kernel<<<1024, 256, 0, stream>>>(xt, wfrag, bnp, out);
    } else {
        dim3 gridc(HH, NB);
        conv_kernel<<<gridc, 256, 0, stream>>>(x, Wall, opidx, out);
        stats_kernel<<<FF, 256, 0, stream>>>(out, gamma, beta, ws);
        apply_kernel<<<2048, 256, 0, stream>>>(out, ws);
    }
}

// Round 8
// 45.711 us; speedup vs baseline: 2.3399x; 1.0406x over previous
//
#include <hip/hip_runtime.h>

#define NB   16
#define CINC 32
#define HH   128
#define WWD  128
#define FF   32
#define OPSN 5
#define EPSV 1e-5f

// ws layout:
//   floats [0:64)          bnp (scale/shift)
//   floats [64:65600)      partial (1024 blocks * 64)
//   bytes  at 262400       wfrag (18 frags * 64 lanes * 8 bf16 = 18432 B)
//   bytes  at 280832       xt  [16][130][130][32] bf16
#define WS_PARTIAL_FOFF 64
#define WS_WFRAG_BOFF   262400
#define WS_XT_BOFF      280832
#define WS_NEED         (280832 + (size_t)16*130*130*32*2)

typedef __attribute__((ext_vector_type(8))) short bf16x8;
typedef __attribute__((ext_vector_type(4))) float f32x4;
typedef __attribute__((ext_vector_type(4))) unsigned int u32x4;

__device__ __forceinline__ unsigned short f2bf(float f) {
    unsigned u = __builtin_bit_cast(unsigned, f);
    u += 0x7FFFu + ((u >> 16) & 1u);
    return (unsigned short)(u >> 16);
}
__device__ __forceinline__ unsigned pack2(float lo, float hi) {
    return (unsigned)f2bf(lo) | ((unsigned)f2bf(hi) << 16);
}

// ---------------------------------------------------------------------------
// transform: x NCHW fp32 -> xt [n][hp][wp][c] bf16 (halo 0). Block swizzle:
// bid%8 == n>>1 so XCD k produces xt for n in {2k,2k+1}; conv kernels use the
// same mapping -> xt slice (2.16 MB) stays in that XCD's L2.
// x loads are nontemporal (read-once; keep L2 for xt). bid==2080 builds wfrag.
// ---------------------------------------------------------------------------
__global__ __launch_bounds__(256) void transform_kernel(
    const float* __restrict__ x, const float* __restrict__ Wall,
    const int* __restrict__ opidx, unsigned short* __restrict__ xt,
    unsigned short* __restrict__ wfrag)
{
    __shared__ float lds[128 * 35];
    const int bid = blockIdx.x;
    const int tid = threadIdx.x;

    if (bid == NB * 130) {
        // wfrag[((s*2+m)*64+lane)*8+j] = W[f=m*16+(lane&15)][c=(lane>>4)*8+j][kh][kw]
        for (int idx = tid; idx < 9216; idx += 256) {
            int frag = idx >> 9;          // 0..17
            int lane = (idx >> 3) & 63;
            int j    = idx & 7;
            int s = frag >> 1, m = frag & 1;
            int kh = s / 3, kw = s - 3 * kh;
            int f = m * 16 + (lane & 15);
            int c = ((lane >> 4) << 3) + j;
            float v = Wall[((size_t)(f * OPSN + opidx[f]) * 288) + c * 9 + kh * 3 + kw];
            wfrag[idx] = f2bf(v);
        }
        return;
    }

    const int idx = bid >> 3;                      // 0..259
    const int n   = (bid & 7) * 2 + (idx / 130);   // XCD-aligned n
    const int hp  = idx % 130;

    unsigned short* rowp = xt + (size_t)(n * 130 + hp) * 130 * 32;
    uint4 zz = make_uint4(0, 0, 0, 0);

    if (hp == 0 || hp == 129) {
        for (int c = tid; c < 520; c += 256) ((uint4*)rowp)[c] = zz;
        return;
    }

    const int h = hp - 1;
    const float* xr = x + ((size_t)n * CINC * HH + h) * WWD;
    const int c  = tid >> 3;
    const int wq = tid & 7;
#pragma unroll
    for (int it = 0; it < 4; ++it) {
        int w4 = wq + it * 8;
        f32x4 v = __builtin_nontemporal_load(
            (const f32x4*)(xr + (size_t)c * (HH * WWD)) + w4);
        int w = w4 * 4;
        lds[(w + 0) * 35 + c] = v.x;
        lds[(w + 1) * 35 + c] = v.y;
        lds[(w + 2) * 35 + c] = v.z;
        lds[(w + 3) * 35 + c] = v.w;
    }
    __syncthreads();
    for (int cc = tid; cc < 512; cc += 256) {
        int p = cc >> 2, k = cc & 3;
        const float* s = &lds[p * 35 + k * 8];
        uint4 o;
        o.x = pack2(s[0], s[1]); o.y = pack2(s[2], s[3]);
        o.z = pack2(s[4], s[5]); o.w = pack2(s[6], s[7]);
        ((uint4*)rowp)[4 + cc] = o;
    }
    if (tid < 4)       ((uint4*)rowp)[tid] = zz;
    else if (tid < 8)  ((uint4*)rowp)[129 * 4 + tid - 4] = zz;
}

// -------- rolling-row conv helpers -----------------------------------------
// Row R of padded xt feeds outputs h=R (kh0), h=R-1 (kh1), h=R-2 (kh2).
// Streaming 6 rows with a 2-row register window: 18 loads/wave (was 36).
#define LOADROW(f0, f1, f2, R)                                                  \
    {                                                                           \
        const unsigned short* rp =                                              \
            xbase + ((size_t)(R) * 130 + w0) * 32 + laneoff;                    \
        f0 = *(const bf16x8*)(rp);                                              \
        f1 = *(const bf16x8*)(rp + 32);                                         \
        f2 = *(const bf16x8*)(rp + 64);                                         \
    }

#define MROW(f0, f1, f2, aA, aB, kh)                                            \
    {                                                                           \
        aA = __builtin_amdgcn_mfma_f32_16x16x32_bf16(wfr[2*((kh)*3+0)],   f0, aA, 0,0,0); \
        aB = __builtin_amdgcn_mfma_f32_16x16x32_bf16(wfr[2*((kh)*3+0)+1], f0, aB, 0,0,0); \
        aA = __builtin_amdgcn_mfma_f32_16x16x32_bf16(wfr[2*((kh)*3+1)],   f1, aA, 0,0,0); \
        aB = __builtin_amdgcn_mfma_f32_16x16x32_bf16(wfr[2*((kh)*3+1)+1], f1, aB, 0,0,0); \
        aA = __builtin_amdgcn_mfma_f32_16x16x32_bf16(wfr[2*((kh)*3+2)],   f2, aA, 0,0,0); \
        aB = __builtin_amdgcn_mfma_f32_16x16x32_bf16(wfr[2*((kh)*3+2)+1], f2, aB, 0,0,0); \
    }

#define CONV_PROLOGUE                                                           \
    bf16x8 wfr[18];                                                             \
    _Pragma("unroll")                                                           \
    for (int i = 0; i < 18; ++i)                                                \
        wfr[i] = *(const bf16x8*)(wfrag + (i * 64 + lane) * 8);                 \
    const unsigned short* xbase = xt + (size_t)n * 130 * 130 * 32;              \
    const int laneoff = l15 * 32 + lhi * 8;                                     \
    f32x4 zz4 = {0.f, 0.f, 0.f, 0.f};                                           \
    f32x4 a0A = zz4, a0B = zz4, a1A = zz4, a1B = zz4;                           \
    f32x4 a2A = zz4, a2B = zz4, a3A = zz4, a3B = zz4;                           \
    bf16x8 c0, c1, c2, n0, n1, n2;                                              \
    LOADROW(c0, c1, c2, h0);                                                    \
    LOADROW(n0, n1, n2, h0 + 1);

#define CONV_BODY(FIN)                                                          \
    MROW(c0, c1, c2, a0A, a0B, 0);                                              \
    LOADROW(c0, c1, c2, h0 + 2);                                                \
    MROW(n0, n1, n2, a0A, a0B, 1);                                              \
    MROW(n0, n1, n2, a1A, a1B, 0);                                              \
    LOADROW(n0, n1, n2, h0 + 3);                                                \
    MROW(c0, c1, c2, a0A, a0B, 2);                                              \
    MROW(c0, c1, c2, a1A, a1B, 1);                                              \
    MROW(c0, c1, c2, a2A, a2B, 0);                                              \
    FIN(a0A, a0B, 0);                                                           \
    LOADROW(c0, c1, c2, h0 + 4);                                                \
    MROW(n0, n1, n2, a1A, a1B, 2);                                              \
    MROW(n0, n1, n2, a2A, a2B, 1);                                              \
    MROW(n0, n1, n2, a3A, a3B, 0);                                              \
    FIN(a1A, a1B, 1);                                                           \
    LOADROW(n0, n1, n2, h0 + 5);                                                \
    MROW(c0, c1, c2, a2A, a2B, 2);                                              \
    MROW(c0, c1, c2, a3A, a3B, 1);                                              \
    FIN(a2A, a2B, 2);                                                           \
    MROW(n0, n1, n2, a3A, a3B, 2);                                              \
    FIN(a3A, a3B, 3);

// ---------------------------------------------------------------------------
// conv_stats: rolling-row conv into registers -> per-block (sum,sumsq).
// ---------------------------------------------------------------------------
__global__ __launch_bounds__(256) void conv_stats_kernel(
    const unsigned short* __restrict__ xt,
    const unsigned short* __restrict__ wfrag,
    float* __restrict__ partial)
{
    __shared__ float red[4][64];
    const int bid  = blockIdx.x;
    const int tid  = threadIdx.x;
    const int n    = (bid & 7) * 2 + ((bid >> 3) & 1);
    const int rest = bid >> 4;
    const int h0   = (rest & 31) * 4;
    const int wh   = rest >> 5;
    const int lane = tid & 63;
    const int wv   = tid >> 6;
    const int w0   = wh * 64 + wv * 16;
    const int l15  = lane & 15, lhi = lane >> 4;

    float s8[8], q8[8];
#pragma unroll
    for (int j = 0; j < 8; ++j) { s8[j] = 0.f; q8[j] = 0.f; }

#define FIN_STATS(aA, aB, hh)                                                   \
    {                                                                           \
        _Pragma("unroll")                                                       \
        for (int r = 0; r < 4; ++r) {                                           \
            float v0 = aA[r], v1 = aB[r];                                       \
            s8[r]     += v0;  q8[r]     += v0 * v0;                             \
            s8[4 + r] += v1;  q8[4 + r] += v1 * v1;                             \
        }                                                                       \
    }

    CONV_PROLOGUE
    CONV_BODY(FIN_STATS)
#undef FIN_STATS

    // butterfly over the 16 pixel-lanes (xor<16 keeps lhi group intact)
#pragma unroll
    for (int m = 1; m < 16; m <<= 1) {
#pragma unroll
        for (int j = 0; j < 8; ++j) {
            s8[j] += __shfl_xor(s8[j], m, 64);
            q8[j] += __shfl_xor(q8[j], m, 64);
        }
    }
    if (l15 == 0) {
#pragma unroll
        for (int j = 0; j < 8; ++j) {
            int f = (j < 4) ? (lhi * 4 + j) : (16 + lhi * 4 + (j - 4));
            red[wv][f]      = s8[j];
            red[wv][32 + f] = q8[j];
        }
    }
    __syncthreads();
    if (tid < 64)
        partial[(size_t)bid * 64 + tid] =
            red[0][tid] + red[1][tid] + red[2][tid] + red[3][tid];
}

// ---------------------------------------------------------------------------
// stats2: 32 blocks (one per filter) reduce 1024 partials -> scale/shift
// ---------------------------------------------------------------------------
__global__ __launch_bounds__(256) void stats2_kernel(
    const float* __restrict__ partial, const float* __restrict__ gamma,
    const float* __restrict__ beta, float* __restrict__ bnp)
{
    __shared__ float rs[256], rq[256];
    const int f = blockIdx.x;
    const int tid = threadIdx.x;
    float s = 0.f, q = 0.f;
#pragma unroll
    for (int k = 0; k < 4; ++k) {
        const float* p = partial + (size_t)(tid * 4 + k) * 64;
        s += p[f];
        q += p[32 + f];
    }
    rs[tid] = s; rq[tid] = q;
    __syncthreads();
    for (int st = 128; st > 0; st >>= 1) {
        if (tid < st) { rs[tid] += rs[tid + st]; rq[tid] += rq[tid + st]; }
        __syncthreads();
    }
    if (tid == 0) {
        float cnt = (float)(NB * HH * WWD);
        float mean = rs[0] / cnt;
        float var  = rq[0] / cnt - mean * mean;
        float sc = gamma[f] * rsqrtf(var + EPSV);
        bnp[f]      = sc;
        bnp[FF + f] = beta[f] - mean * sc;
    }
}

// ---------------------------------------------------------------------------
// conv_apply: rolling-row conv recompute, fused BN+ReLU, nontemporal final
// write (out is never re-read; keeps xt L2-resident during the pass).
// ---------------------------------------------------------------------------
__global__ __launch_bounds__(256) void conv_apply_kernel(
    const unsigned short* __restrict__ xt,
    const unsigned short* __restrict__ wfrag,
    const float* __restrict__ bnp, float* __restrict__ out)
{
    __shared__ float bns[64];
    const int bid  = blockIdx.x;
    const int tid  = threadIdx.x;
    if (tid < 64) bns[tid] = bnp[tid];

    const int n    = (bid & 7) * 2 + ((bid >> 3) & 1);
    const int rest = bid >> 4;
    const int h0   = (rest & 31) * 4;
    const int wh   = rest >> 5;
    const int lane = tid & 63;
    const int wv   = tid >> 6;
    const int w0   = wh * 64 + wv * 16;
    const int l15  = lane & 15, lhi = lane >> 4;

    __syncthreads();   // bns ready
    float sc0[4], sh0[4], sc1[4], sh1[4];
#pragma unroll
    for (int r = 0; r < 4; ++r) {
        int f0 = lhi * 4 + r, f1 = 16 + lhi * 4 + r;
        sc0[r] = bns[f0]; sh0[r] = bns[32 + f0];
        sc1[r] = bns[f1]; sh1[r] = bns[32 + f1];
    }

    float* ob = out + (size_t)(n * FF + lhi * 4) * (HH * WWD) + h0 * WWD + w0 + l15;

#define FIN_APPLY(aA, aB, hh)                                                   \
    {                                                                           \
        _Pragma("unroll")                                                       \
        for (int r = 0; r < 4; ++r) {                                           \
            __builtin_nontemporal_store(                                        \
                fmaxf(fmaf(aA[r], sc0[r], sh0[r]), 0.f),                        \
                ob + (size_t)r * (HH * WWD) + (hh) * WWD);                      \
            __builtin_nontemporal_store(                                        \
                fmaxf(fmaf(aB[r], sc1[r], sh1[r]), 0.f),                        \
                ob + (size_t)r * (HH * WWD) + 16 * (HH * WWD) + (hh) * WWD);    \
        }                                                                       \
    }

    CONV_PROLOGUE
    CONV_BODY(FIN_APPLY)
#undef FIN_APPLY
}

// ======================= fallback (fp32 VALU, small-ws) =====================
__global__ __launch_bounds__(256) void conv_kernel(
    const float* __restrict__ x, const float* __restrict__ Wall,
    const int* __restrict__ opidx, float* __restrict__ out)
{
    __shared__ float wlds[FF * 289];
    __shared__ float xlds[8 * 3 * 132];
    const int tid = threadIdx.x;
    const int h = blockIdx.x;
    const int n = blockIdx.y;
    for (int i = tid; i < FF * 288; i += 256) {
        int f = i / 288;
        int r = i - f * 288;
        int op = opidx[f];
        wlds[f * 289 + r] = Wall[(f * OPSN + op) * 288 + r];
    }
    const int f = tid & 31;
    const int wg = tid >> 5;
    const int w0 = wg << 4;
    float acc[16];
#pragma unroll
    for (int i = 0; i < 16; ++i) acc[i] = 0.f;
    const float* xn = x + (size_t)n * CINC * HH * WWD;
    for (int cc = 0; cc < 4; ++cc) {
        __syncthreads();
        for (int i = tid; i < 8 * 3 * 132; i += 256) {
            int c8 = i / (3 * 132);
            int rem = i - c8 * (3 * 132);
            int r = rem / 132;
            int wp = rem - r * 132;
            int hin = h + r - 1;
            int win = wp - 1;
            float v = 0.f;
            if ((unsigned)hin < HH && (unsigned)win < WWD)
                v = xn[((cc * 8 + c8) * HH + hin) * WWD + win];
            xlds[i] = v;
        }
        __syncthreads();
#pragma unroll
        for (int c8 = 0; c8 < 8; ++c8) {
            const int c = cc * 8 + c8;
            float wv[9];
#pragma unroll
            for (int k = 0; k < 9; ++k) wv[k] = wlds[f * 289 + c * 9 + k];
#pragma unroll
            for (int kh = 0; kh < 3; ++kh) {
                float xr[20];
                const float4* p = (const float4*)&xlds[(c8 * 3 + kh) * 132 + w0];
#pragma unroll
                for (int j = 0; j < 5; ++j) {
                    float4 v = p[j];
                    xr[j * 4 + 0] = v.x; xr[j * 4 + 1] = v.y;
                    xr[j * 4 + 2] = v.z; xr[j * 4 + 3] = v.w;
                }
#pragma unroll
                for (int kw = 0; kw < 3; ++kw) {
                    float wgt = wv[kh * 3 + kw];
#pragma unroll
                    for (int i = 0; i < 16; ++i)
                        acc[i] = fmaf(xr[i + kw], wgt, acc[i]);
                }
            }
        }
    }
    float* op_ = out + (((size_t)(n * FF + f) * HH + h) * WWD + w0);
#pragma unroll
    for (int j = 0; j < 4; ++j)
        ((float4*)op_)[j] = make_float4(acc[j * 4], acc[j * 4 + 1],
                                        acc[j * 4 + 2], acc[j * 4 + 3]);
}

__global__ __launch_bounds__(256) void stats_kernel(
    const float* __restrict__ out, const float* __restrict__ gamma,
    const float* __restrict__ beta, float* __restrict__ ws)
{
    __shared__ float ssum[256], ssq[256];
    const int f = blockIdx.x;
    const int tid = threadIdx.x;
    float s = 0.f, q = 0.f;
    for (int n = 0; n < NB; ++n) {
        const float4* p = (const float4*)(out + (size_t)(n * FF + f) * HH * WWD);
        for (int i = tid; i < HH * WWD / 4; i += 256) {
            float4 v = p[i];
            s += v.x + v.y + v.z + v.w;
            q += v.x * v.x + v.y * v.y + v.z * v.z + v.w * v.w;
        }
    }
    ssum[tid] = s; ssq[tid] = q;
    __syncthreads();
    for (int st = 128; st > 0; st >>= 1) {
        if (tid < st) { ssum[tid] += ssum[tid + st]; ssq[tid] += ssq[tid + st]; }
        __syncthreads();
    }
    if (tid == 0) {
        float cnt = (float)(NB * HH * WWD);
        float mean = ssum[0] / cnt;
        float var = ssq[0] / cnt - mean * mean;
        float sc = gamma[f] * rsqrtf(var + EPSV);
        ws[f] = sc;
        ws[FF + f] = beta[f] - mean * sc;
    }
}

__global__ __launch_bounds__(256) void apply_kernel(
    float* __restrict__ out, const float* __restrict__ bnp)
{
    const int total4 = NB * FF * HH * WWD / 4;
    for (int i = blockIdx.x * 256 + threadIdx.x; i < total4; i += gridDim.x * 256) {
        int f = (i >> 12) & 31;
        float sc = bnp[f], sh = bnp[FF + f];
        float4 v = ((const float4*)out)[i];
        v.x = fmaxf(fmaf(v.x, sc, sh), 0.f);
        v.y = fmaxf(fmaf(v.y, sc, sh), 0.f);
        v.z = fmaxf(fmaf(v.z, sc, sh), 0.f);
        v.w = fmaxf(fmaf(v.w, sc, sh), 0.f);
        ((float4*)out)[i] = v;
    }
}
// ===========================================================================

extern "C" void kernel_launch(void* const* d_in, const int* in_sizes, int n_in,
                              void* d_out, int out_size, void* d_ws, size_t ws_size,
                              hipStream_t stream) {
    const float* x     = (const float*)d_in[0];
    const float* Wall  = (const float*)d_in[1];
    const float* gamma = (const float*)d_in[2];
    const float* beta  = (const float*)d_in[3];
    const int*   opidx = (const int*)d_in[4];
    float* out = (float*)d_out;
    float* ws  = (float*)d_ws;

    if (ws_size >= WS_NEED) {
        float*          bnp     = ws;
        float*          partial = ws + WS_PARTIAL_FOFF;
        unsigned short* wfrag   = (unsigned short*)((char*)d_ws + WS_WFRAG_BOFF);
        unsigned short* xt      = (unsigned short*)((char*)d_ws + WS_XT_BOFF);

        transform_kernel<<<NB * 130 + 1, 256, 0, stream>>>(x, Wall, opidx, xt, wfrag);
        conv_stats_kernel<<<1024, 256, 0, stream>>>(xt, wfrag, partial);
        stats2_kernel<<<FF, 256, 0, stream>>>(partial, gamma, beta, bnp);
        conv_apply_kernel<<<1024, 256, 0, stream>>>(xt, wfrag, bnp, out);
    } else {
        dim3 gridc(HH, NB);
        conv_kernel<<<gridc, 256, 0, stream>>>(x, Wall, opidx, out);
        stats_kernel<<<FF, 256, 0, stream>>>(out, gamma, beta, ws);
        apply_kernel<<<2048, 256, 0, stream>>>(out, ws);
    }
}